// Round 16
// baseline (331.269 us; speedup 1.0000x reference)
//
#include <hip/hip_runtime.h>
#include <hip/hip_bf16.h>
#include <float.h>

// DensityLoss: B=4, N=8192, D=3, K=10 NN (excluding self).
// avg = sum(sqrt of 11 smallest d^2 incl. self))/10; out = mean_b var_ddof1.
//
// R13: x-sorted window scan (exact). Kernel A bins points by x (counting
// sort, 1024 uniform bins on [-8,8); within-bin order arbitrary). Kernel B:
// block = 64 consecutive sorted queries (lane = query), 8 waves scan
// outward with stride 8 in both directions, branchless int top-11 network.
// Exit: all unvisited right points have x >= x_last - BINW, so once
// (x_last - xq) >= sqrt(cap) + BINW nothing right can enter the top-11
// (cap = min over waves of 11th-smallest-so-far >= true 11th d^2); same
// left. Self (d=0) pre-inserted by wave 0. Bounded rounds => worst case
// degrades to exhaustive scan (still exact). Fallback to R11 exhaustive
// kernel if ws_size < 516 KB.

#define N_PTS 8192
#define NB 4
#define KNN 11
#define IPOSINF 0x7F800000
#define BINW_MARGIN 0.016f              // > 16/1024 bin width
#define SCAN_BLOCKS (NB * (N_PTS / 64)) // 512
#define SCAN_THREADS 512
#define SWAVES 8
#define SMERGE_STRIDE (SWAVES * KNN + 1) // 89

__device__ __forceinline__ int imin2(int a, int b) { return a < b ? a : b; }
__device__ __forceinline__ int imax2(int a, int b) { return a > b ? a : b; }

__device__ __forceinline__ void insert_pair_i(int* w, float da, float db) {
  const int ia = __float_as_int(da);
  const int ib = __float_as_int(db);
  const int lo = imin2(ia, ib);
  const int hi = imax2(ia, ib);
#pragma unroll
  for (int s = 0; s < KNN; ++s)
    w[s] = imax2(imax2(w[s + 2], imin2(w[s + 1], hi)), imin2(w[s], lo));
}

// ---------------- Kernel A: counting-sort by x into float4 array ----------
__global__ __launch_bounds__(1024) void binsort_kernel(
    const float* __restrict__ pc, float4* __restrict__ out4) {
  __shared__ int hist[1024];
  __shared__ int offs[1024];
  const int b = blockIdx.x;
  const int tid = threadIdx.x;
  const float* __restrict__ batch = pc + (size_t)b * (N_PTS * 3);

  hist[tid] = 0;
  __syncthreads();
  for (int i = tid; i < N_PTS; i += 1024) {
    const float x = batch[i * 3];
    int bin = (int)((x + 8.0f) * 64.0f);
    bin = min(max(bin, 0), 1023);
    atomicAdd(&hist[bin], 1);
  }
  __syncthreads();
  // inclusive scan (Hillis-Steele) -> exclusive starts
  offs[tid] = hist[tid];
  __syncthreads();
  for (int off = 1; off < 1024; off <<= 1) {
    const int t = (tid >= off) ? offs[tid - off] : 0;
    __syncthreads();
    offs[tid] += t;
    __syncthreads();
  }
  const int start = offs[tid] - hist[tid];
  __syncthreads();
  offs[tid] = start;
  __syncthreads();
  for (int i = tid; i < N_PTS; i += 1024) {
    const float x = batch[i * 3 + 0];
    const float y = batch[i * 3 + 1];
    const float z = batch[i * 3 + 2];
    int bin = (int)((x + 8.0f) * 64.0f);
    bin = min(max(bin, 0), 1023);
    const int pos = atomicAdd(&offs[bin], 1);
    out4[b * N_PTS + pos] = make_float4(x, y, z, 0.0f);
  }
}

// ---------------- Kernel B: windowed scan + fused variance ----------------
__global__ __launch_bounds__(SCAN_THREADS) void scan_kernel(
    const float4* __restrict__ sorted4, double* __restrict__ wsd,
    unsigned int* __restrict__ done_cnt, float* __restrict__ out) {
  __shared__ int sMerge[64 * SMERGE_STRIDE];
  __shared__ int sThr[SWAVES][64];
  __shared__ int sAct[SWAVES];

  const int b = blockIdx.x >> 7;
  const int rowBase = (blockIdx.x & 127) << 6;
  const int tid = threadIdx.x;
  const int wid = __builtin_amdgcn_readfirstlane(tid >> 6);
  const int lane = tid & 63;
  const int p = rowBase + lane;
  const float4* __restrict__ base = sorted4 + b * N_PTS;
  const float4 q = base[p];
  const float INFf = __int_as_float(IPOSINF);

  int w[KNN + 2];
#pragma unroll
  for (int s = 0; s < KNN; ++s) w[s] = IPOSINF;
  w[KNN] = -1;
  w[KNN + 1] = -1;
  if (wid == 0) insert_pair_i(w, 0.0f, INFf);  // self, d^2 = 0

  int jr = p + 1 + wid;
  int jl = p - 1 - wid;
  float ldxr = 0.0f, ldxl = 0.0f;

  for (int round = 0; round < 520; ++round) {
#pragma unroll
    for (int st = 0; st < 8; ++st) {
      const bool okr = (jr < N_PTS);
      const float4 cr = base[okr ? jr : N_PTS - 1];
      float dxr = cr.x - q.x;
      const float dyr = cr.y - q.y, dzr = cr.z - q.z;
      float d2r = fmaf(dxr, dxr, fmaf(dyr, dyr, dzr * dzr));
      d2r = okr ? d2r : INFf;
      dxr = okr ? dxr : INFf;

      const bool okl = (jl >= 0);
      const float4 cl = base[okl ? jl : 0];
      float dxl = q.x - cl.x;
      const float dyl = cl.y - q.y, dzl = cl.z - q.z;
      float d2l = fmaf(dxl, dxl, fmaf(dyl, dyl, dzl * dzl));
      d2l = okl ? d2l : INFf;
      dxl = okl ? dxl : INFf;

      insert_pair_i(w, d2r, d2l);
      ldxr = dxr;
      ldxl = dxl;
      jr += SWAVES;
      jl -= SWAVES;
    }
    // share caps + block-wide activity
    sThr[wid][lane] = w[0];
    __syncthreads();
    int cap = sThr[0][lane];
#pragma unroll
    for (int u = 1; u < SWAVES; ++u) cap = imin2(cap, sThr[u][lane]);
    const float rcap = sqrtf(__int_as_float(cap)) + BINW_MARGIN;
    const int act = (ldxr < rcap) || (ldxl < rcap);
    const unsigned long long m = __ballot(act);
    if (lane == 0) sAct[wid] = (m != 0ULL) ? 1 : 0;
    __syncthreads();
    int any = 0;
#pragma unroll
    for (int u = 0; u < SWAVES; ++u) any |= sAct[u];
    if (!any) break;
  }

  // merge 8 waves' top-11 per query
#pragma unroll
  for (int s = 0; s < KNN; ++s)
    sMerge[lane * SMERGE_STRIDE + wid * KNN + s] = w[s];
  __syncthreads();

  if (tid < 64) {
    int best[KNN + 2];
#pragma unroll
    for (int s = 0; s < KNN; ++s) best[s] = IPOSINF;
    best[KNN] = -1;
    best[KNN + 1] = -1;
    const int* m = &sMerge[tid * SMERGE_STRIDE];
#pragma unroll 2
    for (int c = 0; c < SWAVES * KNN; c += 2) {
      const int ia = m[c];
      const int ib = m[c + 1];
      const int lo = imin2(ia, ib);
      const int hi = imax2(ia, ib);
#pragma unroll
      for (int s = 0; s < KNN; ++s)
        best[s] = imax2(imax2(best[s + 2], imin2(best[s + 1], hi)),
                        imin2(best[s], lo));
    }
    float sum = 0.0f;
#pragma unroll
    for (int s = 0; s < KNN; ++s) sum += sqrtf(__int_as_float(best[s]));
    const double avg = (double)(sum * (1.0f / 10.0f));

    double S = avg, S2 = avg * avg;
#pragma unroll
    for (int off = 32; off > 0; off >>= 1) {
      S += __shfl_down(S, off, 64);
      S2 += __shfl_down(S2, off, 64);
    }
    if (tid == 0) {
      atomicAdd(&wsd[2 * b + 0], S);
      atomicAdd(&wsd[2 * b + 1], S2);
    }
  }

  if (tid == 0) {
    __threadfence();
    const unsigned int old = atomicAdd(done_cnt, 1u);
    if (old == SCAN_BLOCKS - 1) {
      double total = 0.0;
#pragma unroll
      for (int bb = 0; bb < NB; ++bb) {
        const double S = atomicAdd(&wsd[2 * bb + 0], 0.0);
        const double S2 = atomicAdd(&wsd[2 * bb + 1], 0.0);
        total += (S2 - S * S / (double)N_PTS) / (double)(N_PTS - 1);
      }
      out[0] = (float)(total / NB);
    }
  }
}

// ---------------- Fallback: R11 exhaustive kernel (ws too small) ----------
#define FTHREADS 1024
#define FWAVES 16
#define FCPW (N_PTS / FWAVES)
#define FSTRIDE (FWAVES * KNN + 1)
#define FBLOCKS (NB * (N_PTS / 64))

__global__ __launch_bounds__(FTHREADS, 8) void knn_fused_kernel(
    const float* __restrict__ pc, double* __restrict__ wsd,
    unsigned int* __restrict__ done_cnt, float* __restrict__ out) {
  __shared__ int sM[64 * FSTRIDE];
  const int b = blockIdx.x >> 7;
  const int rowBase = (blockIdx.x & 127) << 6;
  const int tid = threadIdx.x;
  const int wid = __builtin_amdgcn_readfirstlane(tid >> 6);
  const int lane = tid & 63;
  const int row = rowBase + lane;
  const float* __restrict__ batch = pc + (size_t)b * (N_PTS * 3);
  const float xi = batch[row * 3 + 0];
  const float yi = batch[row * 3 + 1];
  const float zi = batch[row * 3 + 2];
  int w[KNN + 2];
#pragma unroll
  for (int s = 0; s < KNN; ++s) w[s] = IPOSINF;
  w[KNN] = -1;
  w[KNN + 1] = -1;
  const float* __restrict__ cp = batch + wid * (FCPW * 3);
#pragma unroll 4
  for (int j = 0; j < FCPW; j += 2) {
    const float ax = cp[0], ay = cp[1], az = cp[2];
    const float bx = cp[3], by = cp[4], bz = cp[5];
    cp += 6;
    const float dax = xi - ax, day = yi - ay, daz = zi - az;
    const float dbx = xi - bx, dby = yi - by, dbz = zi - bz;
    insert_pair_i(w, fmaf(dax, dax, fmaf(day, day, daz * daz)),
                  fmaf(dbx, dbx, fmaf(dby, dby, dbz * dbz)));
  }
#pragma unroll
  for (int s = 0; s < KNN; ++s) sM[lane * FSTRIDE + wid * KNN + s] = w[s];
  __syncthreads();
  if (tid < 64) {
    int best[KNN + 2];
#pragma unroll
    for (int s = 0; s < KNN; ++s) best[s] = IPOSINF;
    best[KNN] = -1;
    best[KNN + 1] = -1;
    const int* m = &sM[tid * FSTRIDE];
#pragma unroll 2
    for (int c = 0; c < FWAVES * KNN; c += 2) {
      const int ia = m[c], ib = m[c + 1];
      const int lo = imin2(ia, ib), hi = imax2(ia, ib);
#pragma unroll
      for (int s = 0; s < KNN; ++s)
        best[s] = imax2(imax2(best[s + 2], imin2(best[s + 1], hi)),
                        imin2(best[s], lo));
    }
    float sum = 0.0f;
#pragma unroll
    for (int s = 0; s < KNN; ++s) sum += sqrtf(__int_as_float(best[s]));
    const double avg = (double)(sum * (1.0f / 10.0f));
    double S = avg, S2 = avg * avg;
#pragma unroll
    for (int off = 32; off > 0; off >>= 1) {
      S += __shfl_down(S, off, 64);
      S2 += __shfl_down(S2, off, 64);
    }
    if (tid == 0) {
      atomicAdd(&wsd[2 * b + 0], S);
      atomicAdd(&wsd[2 * b + 1], S2);
    }
  }
  if (tid == 0) {
    __threadfence();
    const unsigned int old = atomicAdd(done_cnt, 1u);
    if (old == FBLOCKS - 1) {
      double total = 0.0;
#pragma unroll
      for (int bb = 0; bb < NB; ++bb) {
        const double S = atomicAdd(&wsd[2 * bb + 0], 0.0);
        const double S2 = atomicAdd(&wsd[2 * bb + 1], 0.0);
        total += (S2 - S * S / (double)N_PTS) / (double)(N_PTS - 1);
      }
      out[0] = (float)(total / NB);
    }
  }
}

extern "C" void kernel_launch(void* const* d_in, const int* in_sizes, int n_in,
                              void* d_out, int out_size, void* d_ws,
                              size_t ws_size, hipStream_t stream) {
  const float* pc = (const float*)d_in[0];
  float* out = (float*)d_out;

  const size_t sorted_bytes = (size_t)NB * N_PTS * sizeof(float4);  // 512 KB
  const size_t need = sorted_bytes + 2 * NB * sizeof(double) + 64;

  if (ws_size >= need) {
    float4* sorted4 = (float4*)d_ws;
    double* wsd = (double*)((char*)d_ws + sorted_bytes);
    unsigned int* done_cnt =
        (unsigned int*)((char*)d_ws + sorted_bytes + 2 * NB * sizeof(double));
    hipMemsetAsync((char*)d_ws + sorted_bytes, 0,
                   2 * NB * sizeof(double) + sizeof(unsigned int), stream);
    binsort_kernel<<<NB, 1024, 0, stream>>>(pc, sorted4);
    scan_kernel<<<SCAN_BLOCKS, SCAN_THREADS, 0, stream>>>(sorted4, wsd,
                                                          done_cnt, out);
  } else {
    double* wsd = (double*)d_ws;
    unsigned int* done_cnt =
        (unsigned int*)((char*)d_ws + 2 * NB * sizeof(double));
    hipMemsetAsync(d_ws, 0, 2 * NB * sizeof(double) + sizeof(unsigned int),
                   stream);
    knn_fused_kernel<<<FBLOCKS, FTHREADS, 0, stream>>>(pc, wsd, done_cnt, out);
  }
}